// Round 1
// baseline (592.019 us; speedup 1.0000x reference)
//
#include <hip/hip_runtime.h>
#include <hip/hip_bf16.h>
#include <stdint.h>

#define M_DIM 8192   // 4*2048 rows of x
#define K_DIM 4096   // in_features
#define N_DIM 4096   // out_features

typedef __attribute__((ext_vector_type(8))) short short8;
typedef __attribute__((ext_vector_type(4))) float floatx4;

__device__ inline unsigned short f2bf(float f) {
    union { float f; unsigned int u; } v; v.f = f;
    unsigned int u = v.u;
    u += 0x7fffu + ((u >> 16) & 1u);   // round-to-nearest-even
    return (unsigned short)(u >> 16);
}

// ---------------- kernel 1: cast x fp32 -> bf16 ----------------
__global__ __launch_bounds__(256)
void conv_x(const float* __restrict__ x, unsigned short* __restrict__ xb) {
    const size_t idx = ((size_t)blockIdx.x * 256 + threadIdx.x) * 4;
    float4 v = *(const float4*)(x + idx);
    ushort4 o;
    o.x = f2bf(v.x); o.y = f2bf(v.y); o.z = f2bf(v.z); o.w = f2bf(v.w);
    *(ushort4*)(xb + idx) = o;
}

// ---------------- kernel 2: reconstruct W (bf16, [N][K] = B^T layout) ------
// stacked[n][p][c] = dot(vq[n][p][:32], wdec[p][:32][c]) + bdec[p][c]
// W[p*1024 + n/16][(n%16)*256 + c] = stacked*(d_std[p]+eps) + d_mean[p]
__global__ __launch_bounds__(256)
void gen_w(const float* __restrict__ vq, const float* __restrict__ wdec,
           const float* __restrict__ bdec, const float* __restrict__ dmean,
           const float* __restrict__ dstd, unsigned short* __restrict__ W) {
    const int c = threadIdx.x;           // 0..255
    const int p = blockIdx.y;            // 0..3
    const int nbase = blockIdx.x * 64;   // grid.x = 256 -> 16384 n total

    float wl[32];
    #pragma unroll
    for (int l = 0; l < 32; l++) wl[l] = wdec[(p * 32 + l) * 256 + c];
    const float bb    = bdec[p * 256 + c];
    const float scale = dstd[p] + 1e-6f;
    const float mean  = dmean[p];

    for (int nn = 0; nn < 64; nn++) {
        const int n = nbase + nn;
        const float* v = vq + ((size_t)n * 4 + p) * 32;   // block-uniform ptr
        float s = 0.f;
        #pragma unroll
        for (int l = 0; l < 32; l++) s = fmaf(v[l], wl[l], s);
        s = (s + bb) * scale + mean;
        const int o = (p << 10) + (n >> 4);
        const int q = ((n & 15) << 8) + c;
        W[(size_t)o * K_DIM + q] = f2bf(s);
    }
}

// ---------------- kernel 3: C[M][N] = A[M][K] * B[N][K]^T + bias -----------
__device__ inline void async16(const unsigned short* g, unsigned short* l) {
    __builtin_amdgcn_global_load_lds(
        (const __attribute__((address_space(1))) void*)g,
        (__attribute__((address_space(3))) void*)l, 16, 0, 0);
}

__global__ __launch_bounds__(256, 2)
void gemm_bt(const unsigned short* __restrict__ A,
             const unsigned short* __restrict__ B,
             const float* __restrict__ bias,
             float* __restrict__ C) {
    __shared__ unsigned short sA[128 * 32];   // row-major, row stride 32 (no pad: global_load_lds)
    __shared__ unsigned short sB[128 * 32];

    const int tid  = threadIdx.x;
    const int lane = tid & 63;
    const int wave = tid >> 6;
    const int wm = (wave >> 1) * 64;   // wave m-offset in tile
    const int wn = (wave & 1) * 64;    // wave n-offset in tile

    const int m0 = blockIdx.x * 128;
    const int n0 = blockIdx.y * 128;

    // staging: thread t copies 16B; row = t/4, k-elem offset = (t%4)*8
    const int srow = tid >> 2;
    const int scol = (tid & 3) * 8;
    const unsigned short* gA = A + (size_t)(m0 + srow) * K_DIM + scol;
    const unsigned short* gB = B + (size_t)(n0 + srow) * K_DIM + scol;
    unsigned short* lA = sA + tid * 8;   // linear: wave-uniform base + lane*16B
    unsigned short* lB = sB + tid * 8;

    // fragment read addresses
    const int fr = lane & 15;
    const int kq = (lane >> 4) * 8;
    const unsigned short* fA = sA + (wm + fr) * 32 + kq;
    const unsigned short* fB = sB + (wn + fr) * 32 + kq;

    floatx4 acc[4][4] = {};

    for (int k0 = 0; k0 < K_DIM; k0 += 32) {
        __syncthreads();                       // prior frag reads done before overwrite
        async16(gA + k0,                        lA);
        async16(gA + k0 + (size_t)64 * K_DIM,   lA + 64 * 32);
        async16(gB + k0,                        lB);
        async16(gB + k0 + (size_t)64 * K_DIM,   lB + 64 * 32);
        __syncthreads();                       // compiler emits vmcnt(0) drain here

        short8 av[4], bv[4];
        #pragma unroll
        for (int i = 0; i < 4; i++) av[i] = *(const short8*)(fA + i * 16 * 32);
        #pragma unroll
        for (int i = 0; i < 4; i++) bv[i] = *(const short8*)(fB + i * 16 * 32);
        #pragma unroll
        for (int mi = 0; mi < 4; mi++)
            #pragma unroll
            for (int ni = 0; ni < 4; ni++)
                acc[mi][ni] = __builtin_amdgcn_mfma_f32_16x16x32_bf16(
                    av[mi], bv[ni], acc[mi][ni], 0, 0, 0);
    }

    // epilogue: C/D layout col = lane&15, row = (lane>>4)*4 + reg   [m89]
    const int rq = (lane >> 4) * 4;
    #pragma unroll
    for (int ni = 0; ni < 4; ni++) {
        const int n = n0 + wn + ni * 16 + fr;
        const float bv_add = bias[n];
        #pragma unroll
        for (int mi = 0; mi < 4; mi++) {
            const int m = m0 + wm + mi * 16 + rq;
            float* cp = C + (size_t)m * N_DIM + n;
            #pragma unroll
            for (int r = 0; r < 4; r++)
                cp[(size_t)r * N_DIM] = acc[mi][ni][r] + bv_add;
        }
    }
}

extern "C" void kernel_launch(void* const* d_in, const int* in_sizes, int n_in,
                              void* d_out, int out_size, void* d_ws, size_t ws_size,
                              hipStream_t stream) {
    const float* x     = (const float*)d_in[0];   // (4,2048,4096)
    const float* vq    = (const float*)d_in[1];   // (16384,4,32)
    const float* wdec  = (const float*)d_in[2];   // (4,32,256)
    const float* bdec  = (const float*)d_in[3];   // (4,256)
    const float* dmean = (const float*)d_in[4];   // (4,1)
    const float* dstd  = (const float*)d_in[5];   // (4,1)
    const float* bias  = (const float*)d_in[6];   // (4096,)
    float* out = (float*)d_out;

    unsigned short* xb = (unsigned short*)d_ws;                 // 8192*4096 bf16 = 64 MiB
    unsigned short* wb = xb + (size_t)M_DIM * K_DIM;            // 4096*4096 bf16 = 32 MiB

    // 1) x -> bf16
    conv_x<<<(M_DIM * (size_t)K_DIM) / 4 / 256, 256, 0, stream>>>(x, xb);
    // 2) reconstruct W in bf16 [N][K]
    gen_w<<<dim3(256, 4), 256, 0, stream>>>(vq, wdec, bdec, dmean, dstd, wb);
    // 3) big GEMM + bias
    gemm_bt<<<dim3(M_DIM / 128, N_DIM / 128), 256, 0, stream>>>(xb, wb, bias, out);
}

// Round 2
// 438.503 us; speedup vs baseline: 1.3501x; 1.3501x over previous
//
#include <hip/hip_runtime.h>
#include <hip/hip_bf16.h>
#include <stdint.h>

#define M_DIM 8192   // 4*2048 rows of x
#define K_DIM 4096   // in_features
#define N_DIM 4096   // out_features

typedef __attribute__((ext_vector_type(4))) int int4v;

__device__ inline int q8(float v, float inv) {
    int q = (int)__builtin_rintf(v * inv);
    return max(-127, min(127, q));
}

// ---------------- kernel 1: quantize x rows to i8 (per-row scale) ----------
// one block per row; 4 passes of float4 per thread
__global__ __launch_bounds__(256)
void quant_x(const float* __restrict__ x, signed char* __restrict__ qx,
             float* __restrict__ sx) {
    const int r = blockIdx.x;
    const int tid = threadIdx.x;
    const size_t base = (size_t)r * K_DIM;

    float4 v[4];
    float amax = 0.f;
    #pragma unroll
    for (int j = 0; j < 4; j++) {
        v[j] = *(const float4*)(x + base + j * 1024 + tid * 4);
        amax = fmaxf(amax, fmaxf(fmaxf(fabsf(v[j].x), fabsf(v[j].y)),
                                 fmaxf(fabsf(v[j].z), fabsf(v[j].w))));
    }
    __shared__ float red[256];
    red[tid] = amax;
    __syncthreads();
    for (int s = 128; s > 0; s >>= 1) {
        if (tid < s) red[tid] = fmaxf(red[tid], red[tid + s]);
        __syncthreads();
    }
    const float am = fmaxf(red[0], 1e-30f);
    const float inv = 127.f / am;
    if (tid == 0) sx[r] = am / 127.f;

    #pragma unroll
    for (int j = 0; j < 4; j++) {
        int a = q8(v[j].x, inv), b = q8(v[j].y, inv),
            c = q8(v[j].z, inv), d = q8(v[j].w, inv);
        unsigned int pk = (a & 0xff) | ((b & 0xff) << 8) |
                          ((c & 0xff) << 16) | ((d & 0xff) << 24);
        *(unsigned int*)(qx + base + j * 1024 + tid * 4) = pk;
    }
}

// ---------------- kernel 2: reconstruct W row, quantize to i8 --------------
// one block per W-row o (4096 blocks). Row o covers n in [t*16, t*16+16),
// c in [0,256): W[o][nn*256+c] = (dot(vq[n][p],wdec[p][:,c]) + bdec[p][c])
//                                * (dstd[p]+eps) + dmean[p]
__global__ __launch_bounds__(256)
void gen_w_q8(const float* __restrict__ vq, const float* __restrict__ wdec,
              const float* __restrict__ bdec, const float* __restrict__ dmean,
              const float* __restrict__ dstd, signed char* __restrict__ qw,
              float* __restrict__ sw) {
    const int o = blockIdx.x;
    const int c = threadIdx.x;
    const int p = o >> 10;
    const int t = o & 1023;

    __shared__ float vql[16 * 32];   // vq[t*16+nn][p][l]
    #pragma unroll
    for (int f = c; f < 512; f += 256) {
        const int nn = f >> 5, l = f & 31;
        vql[f] = vq[((size_t)(t * 16 + nn) * 4 + p) * 32 + l];
    }

    float wl[32];
    #pragma unroll
    for (int l = 0; l < 32; l++) wl[l] = wdec[(p * 32 + l) * 256 + c];
    const float bb    = bdec[p * 256 + c];
    const float scale = dstd[p] + 1e-6f;
    const float mean  = dmean[p];
    __syncthreads();

    float val[16];
    float amax = 0.f;
    #pragma unroll
    for (int nn = 0; nn < 16; nn++) {
        float s = 0.f;
        #pragma unroll
        for (int l = 0; l < 32; l++) s = fmaf(vql[nn * 32 + l], wl[l], s);
        val[nn] = (s + bb) * scale + mean;
        amax = fmaxf(amax, fabsf(val[nn]));
    }
    __shared__ float red[256];
    red[c] = amax;
    __syncthreads();
    for (int s = 128; s > 0; s >>= 1) {
        if (c < s) red[c] = fmaxf(red[c], red[c + s]);
        __syncthreads();
    }
    const float am = fmaxf(red[0], 1e-30f);
    const float inv = 127.f / am;
    if (c == 0) sw[o] = am / 127.f;

    signed char* row = qw + (size_t)o * K_DIM;
    #pragma unroll
    for (int nn = 0; nn < 16; nn++)
        row[nn * 256 + c] = (signed char)q8(val[nn], inv);
}

// ---------------- kernel 3: C = dequant(QA * QB^T) + bias ------------------
__device__ inline void async16(const void* g, void* l) {
    __builtin_amdgcn_global_load_lds(
        (const __attribute__((address_space(1))) void*)g,
        (__attribute__((address_space(3))) void*)l, 16, 0, 0);
}

__global__ __launch_bounds__(256, 2)
void gemm_i8(const signed char* __restrict__ A,   // [M][K] i8
             const signed char* __restrict__ B,   // [N][K] i8
             const float* __restrict__ sx,        // [M]
             const float* __restrict__ sw,        // [N]
             const float* __restrict__ bias,      // [N]
             float* __restrict__ C) {
    __shared__ signed char sAl[128 * 64];   // row stride 64 B (BK=64, no pad)
    __shared__ signed char sBl[128 * 64];

    const int tid  = threadIdx.x;
    const int lane = tid & 63;
    const int wave = tid >> 6;
    const int wm = (wave >> 1) * 64;
    const int wn = (wave & 1) * 64;

    const int m0 = blockIdx.x * 128;
    const int n0 = blockIdx.y * 128;

    // staging: thread t copies 16 B; row = t/4 (0..63), k-offset = (t%4)*16
    const int srow = tid >> 2;
    const int scol = (tid & 3) * 16;
    const signed char* gA = A + (size_t)(m0 + srow) * K_DIM + scol;
    const signed char* gB = B + (size_t)(n0 + srow) * K_DIM + scol;
    signed char* lA = sAl + tid * 16;   // linear: matches row*64 + scol
    signed char* lB = sBl + tid * 16;

    // fragment addresses: m = lane&15, k = (lane>>4)*16 + j  (j in [0,16))
    const int fr = lane & 15;
    const int kq = (lane >> 4) * 16;
    const signed char* fA = sAl + (wm + fr) * 64 + kq;
    const signed char* fB = sBl + (wn + fr) * 64 + kq;

    int4v acc[4][4] = {};

    for (int k0 = 0; k0 < K_DIM; k0 += 64) {
        __syncthreads();
        async16(gA + k0,                        lA);
        async16(gA + k0 + (size_t)64 * K_DIM,   lA + 64 * 64);
        async16(gB + k0,                        lB);
        async16(gB + k0 + (size_t)64 * K_DIM,   lB + 64 * 64);
        __syncthreads();

        int4v av[4], bv[4];
        #pragma unroll
        for (int i = 0; i < 4; i++) av[i] = *(const int4v*)(fA + i * 16 * 64);
        #pragma unroll
        for (int i = 0; i < 4; i++) bv[i] = *(const int4v*)(fB + i * 16 * 64);
        #pragma unroll
        for (int mi = 0; mi < 4; mi++)
            #pragma unroll
            for (int ni = 0; ni < 4; ni++)
                acc[mi][ni] = __builtin_amdgcn_mfma_i32_16x16x64_i8(
                    av[mi], bv[ni], acc[mi][ni], 0, 0, 0);
    }

    // epilogue: C/D layout col = lane&15, row = (lane>>4)*4 + reg (dtype-indep)
    const int rq = (lane >> 4) * 4;
    #pragma unroll
    for (int ni = 0; ni < 4; ni++) {
        const int n = n0 + wn + ni * 16 + fr;
        const float swn = sw[n];
        const float bn  = bias[n];
        #pragma unroll
        for (int mi = 0; mi < 4; mi++) {
            const int mb = m0 + wm + mi * 16 + rq;
            float* cp = C + (size_t)mb * N_DIM + n;
            #pragma unroll
            for (int r = 0; r < 4; r++)
                cp[(size_t)r * N_DIM] =
                    (float)acc[mi][ni][r] * sx[mb + r] * swn + bn;
        }
    }
}

extern "C" void kernel_launch(void* const* d_in, const int* in_sizes, int n_in,
                              void* d_out, int out_size, void* d_ws, size_t ws_size,
                              hipStream_t stream) {
    const float* x     = (const float*)d_in[0];   // (4,2048,4096)
    const float* vq    = (const float*)d_in[1];   // (16384,4,32)
    const float* wdec  = (const float*)d_in[2];   // (4,32,256)
    const float* bdec  = (const float*)d_in[3];   // (4,256)
    const float* dmean = (const float*)d_in[4];   // (4,1)
    const float* dstd  = (const float*)d_in[5];   // (4,1)
    const float* bias  = (const float*)d_in[6];   // (4096,)
    float* out = (float*)d_out;

    signed char* qx = (signed char*)d_ws;                      // 33.55 MB
    signed char* qw = qx + (size_t)M_DIM * K_DIM;              // 16.78 MB
    float* sx = (float*)(qw + (size_t)N_DIM * K_DIM);          // 32 KB
    float* sw = sx + M_DIM;                                    // 16 KB

    quant_x<<<M_DIM, 256, 0, stream>>>(x, qx, sx);
    gen_w_q8<<<N_DIM, 256, 0, stream>>>(vq, wdec, bdec, dmean, dstd, qw, sw);
    gemm_i8<<<dim3(M_DIM / 128, N_DIM / 128), 256, 0, stream>>>(
        qx, qw, sx, sw, bias, out);
}

// Round 3
// 432.057 us; speedup vs baseline: 1.3702x; 1.0149x over previous
//
#include <hip/hip_runtime.h>
#include <hip/hip_bf16.h>
#include <stdint.h>

#define M_DIM 8192   // 4*2048 rows of x
#define K_DIM 4096   // in_features
#define N_DIM 4096   // out_features

typedef __attribute__((ext_vector_type(4))) int int4v;

__device__ inline int q8(float v, float inv) {
    int q = (int)__builtin_rintf(v * inv);
    return max(-127, min(127, q));
}

// ---------------- kernel 1: quantize x rows to i8 (per-row scale) ----------
__global__ __launch_bounds__(256)
void quant_x(const float* __restrict__ x, signed char* __restrict__ qx,
             float* __restrict__ sx) {
    const int r = blockIdx.x;
    const int tid = threadIdx.x;
    const size_t base = (size_t)r * K_DIM;

    float4 v[4];
    float amax = 0.f;
    #pragma unroll
    for (int j = 0; j < 4; j++) {
        v[j] = *(const float4*)(x + base + j * 1024 + tid * 4);
        amax = fmaxf(amax, fmaxf(fmaxf(fabsf(v[j].x), fabsf(v[j].y)),
                                 fmaxf(fabsf(v[j].z), fabsf(v[j].w))));
    }
    __shared__ float red[256];
    red[tid] = amax;
    __syncthreads();
    for (int s = 128; s > 0; s >>= 1) {
        if (tid < s) red[tid] = fmaxf(red[tid], red[tid + s]);
        __syncthreads();
    }
    const float am = fmaxf(red[0], 1e-30f);
    const float inv = 127.f / am;
    if (tid == 0) sx[r] = am / 127.f;

    #pragma unroll
    for (int j = 0; j < 4; j++) {
        int a = q8(v[j].x, inv), b = q8(v[j].y, inv),
            c = q8(v[j].z, inv), d = q8(v[j].w, inv);
        unsigned int pk = (a & 0xff) | ((b & 0xff) << 8) |
                          ((c & 0xff) << 16) | ((d & 0xff) << 24);
        *(unsigned int*)(qx + base + j * 1024 + tid * 4) = pk;
    }
}

// ---------------- kernel 2: reconstruct W row, quantize to i8 --------------
__global__ __launch_bounds__(256)
void gen_w_q8(const float* __restrict__ vq, const float* __restrict__ wdec,
              const float* __restrict__ bdec, const float* __restrict__ dmean,
              const float* __restrict__ dstd, signed char* __restrict__ qw,
              float* __restrict__ sw) {
    const int o = blockIdx.x;
    const int c = threadIdx.x;
    const int p = o >> 10;
    const int t = o & 1023;

    __shared__ float vql[16 * 32];   // vq[t*16+nn][p][l]
    #pragma unroll
    for (int f = c; f < 512; f += 256) {
        const int nn = f >> 5, l = f & 31;
        vql[f] = vq[((size_t)(t * 16 + nn) * 4 + p) * 32 + l];
    }

    float wl[32];
    #pragma unroll
    for (int l = 0; l < 32; l++) wl[l] = wdec[(p * 32 + l) * 256 + c];
    const float bb    = bdec[p * 256 + c];
    const float scale = dstd[p] + 1e-6f;
    const float mean  = dmean[p];
    __syncthreads();

    float val[16];
    float amax = 0.f;
    #pragma unroll
    for (int nn = 0; nn < 16; nn++) {
        float s = 0.f;
        #pragma unroll
        for (int l = 0; l < 32; l++) s = fmaf(vql[nn * 32 + l], wl[l], s);
        val[nn] = (s + bb) * scale + mean;
        amax = fmaxf(amax, fabsf(val[nn]));
    }
    __shared__ float red[256];
    red[c] = amax;
    __syncthreads();
    for (int s = 128; s > 0; s >>= 1) {
        if (c < s) red[c] = fmaxf(red[c], red[c + s]);
        __syncthreads();
    }
    const float am = fmaxf(red[0], 1e-30f);
    const float inv = 127.f / am;
    if (c == 0) sw[o] = am / 127.f;

    signed char* row = qw + (size_t)o * K_DIM;
    #pragma unroll
    for (int nn = 0; nn < 16; nn++)
        row[nn * 256 + c] = (signed char)q8(val[nn], inv);
}

// ---------------- kernel 3: C = dequant(QA * QB^T) + bias ------------------
__device__ inline void async16(const void* g, void* l) {
    __builtin_amdgcn_global_load_lds(
        (const __attribute__((address_space(1))) void*)g,
        (__attribute__((address_space(3))) void*)l, 16, 0, 0);
}

// __launch_bounds__(256, 4): 4 waves/EU -> 4 blocks/CU; forces allocator to
// <=128 unified regs/wave (acc 64 AGPR + ~56 arch). Round-2 config was 132
// regs -> 3 waves/SIMD cap and only ~2.25 blocks resident (Occupancy 28%).
__global__ __launch_bounds__(256, 4)
void gemm_i8(const signed char* __restrict__ A,   // [M][K] i8
             const signed char* __restrict__ B,   // [N][K] i8
             const float* __restrict__ sx,        // [M]
             const float* __restrict__ sw,        // [N]
             const float* __restrict__ bias,      // [N]
             float* __restrict__ C) {
    __shared__ signed char sAl[128 * 64];   // row stride 64 B (BK=64, no pad)
    __shared__ signed char sBl[128 * 64];

    const int tid  = threadIdx.x;
    const int lane = tid & 63;
    const int wave = tid >> 6;
    const int wm = (wave >> 1) * 64;
    const int wn = (wave & 1) * 64;

    const int m0 = blockIdx.x * 128;
    const int n0 = blockIdx.y * 128;

    // staging: thread t copies 16 B; row = t/4 (0..63), k-offset = (t%4)*16
    const int srow = tid >> 2;
    const int scol = (tid & 3) * 16;
    const signed char* gA = A + (size_t)(m0 + srow) * K_DIM + scol;
    const signed char* gB = B + (size_t)(n0 + srow) * K_DIM + scol;
    signed char* lA = sAl + tid * 16;   // linear: matches row*64 + scol
    signed char* lB = sBl + tid * 16;

    // fragment addresses: m = lane&15, k = (lane>>4)*16 + j  (j in [0,16))
    const int fr = lane & 15;
    const int kq = (lane >> 4) * 16;
    const signed char* fA = sAl + (wm + fr) * 64 + kq;
    const signed char* fB = sBl + (wn + fr) * 64 + kq;

    int4v acc[4][4] = {};

    for (int k0 = 0; k0 < K_DIM; k0 += 64) {
        __syncthreads();
        async16(gA + k0,                        lA);
        async16(gA + k0 + (size_t)64 * K_DIM,   lA + 64 * 64);
        async16(gB + k0,                        lB);
        async16(gB + k0 + (size_t)64 * K_DIM,   lB + 64 * 64);
        __syncthreads();

        // register diet: keep all 4 B-frags live (16 regs) but only one
        // A-frag at a time (4 regs) -> peak frag regs 20 instead of 32.
        int4v bv[4];
        #pragma unroll
        for (int i = 0; i < 4; i++) bv[i] = *(const int4v*)(fB + i * 16 * 64);
        #pragma unroll
        for (int mi = 0; mi < 4; mi++) {
            int4v av = *(const int4v*)(fA + mi * 16 * 64);
            #pragma unroll
            for (int ni = 0; ni < 4; ni++)
                acc[mi][ni] = __builtin_amdgcn_mfma_i32_16x16x64_i8(
                    av, bv[ni], acc[mi][ni], 0, 0, 0);
        }
    }

    // epilogue: C/D layout col = lane&15, row = (lane>>4)*4 + reg (dtype-indep)
    const int rq = (lane >> 4) * 4;
    #pragma unroll
    for (int ni = 0; ni < 4; ni++) {
        const int n = n0 + wn + ni * 16 + fr;
        const float swn = sw[n];
        const float bn  = bias[n];
        #pragma unroll
        for (int mi = 0; mi < 4; mi++) {
            const int mb = m0 + wm + mi * 16 + rq;
            float* cp = C + (size_t)mb * N_DIM + n;
            #pragma unroll
            for (int r = 0; r < 4; r++)
                cp[(size_t)r * N_DIM] =
                    (float)acc[mi][ni][r] * sx[mb + r] * swn + bn;
        }
    }
}

extern "C" void kernel_launch(void* const* d_in, const int* in_sizes, int n_in,
                              void* d_out, int out_size, void* d_ws, size_t ws_size,
                              hipStream_t stream) {
    const float* x     = (const float*)d_in[0];   // (4,2048,4096)
    const float* vq    = (const float*)d_in[1];   // (16384,4,32)
    const float* wdec  = (const float*)d_in[2];   // (4,32,256)
    const float* bdec  = (const float*)d_in[3];   // (4,256)
    const float* dmean = (const float*)d_in[4];   // (4,1)
    const float* dstd  = (const float*)d_in[5];   // (4,1)
    const float* bias  = (const float*)d_in[6];   // (4096,)
    float* out = (float*)d_out;

    signed char* qx = (signed char*)d_ws;                      // 33.55 MB
    signed char* qw = qx + (size_t)M_DIM * K_DIM;              // 16.78 MB
    float* sx = (float*)(qw + (size_t)N_DIM * K_DIM);          // 32 KB
    float* sw = sx + M_DIM;                                    // 16 KB

    quant_x<<<M_DIM, 256, 0, stream>>>(x, qx, sx);
    gen_w_q8<<<N_DIM, 256, 0, stream>>>(vq, wdec, bdec, dmean, dstd, qw, sw);
    gemm_i8<<<dim3(M_DIM / 128, N_DIM / 128), 256, 0, stream>>>(
        qx, qw, sx, sw, bias, out);
}